// Round 4
// baseline (469.342 us; speedup 1.0000x reference)
//
#include <hip/hip_runtime.h>
#include <hip/hip_bf16.h>
#include <math.h>

// Problem constants
#define Ln     35
#define CINn   21
#define CINP   24        // padded CIN (multiple of 8 -> aligned b128 im2col reads)
#define Fn     128
#define Kn     9
#define Hn     64
#define GB     16        // batch rows per block
#define SEQ_STRIDE 1064  // 44 rows*24 + 8 slack (shorts); 16B-aligned rows (48B)
#define TILE_STRIDE 136  // 128 + 8 pad (shorts)
#define YL0    10        // first l whose MLP output is ever consumed
#define NYL    15        // l in [10,24] consumed (plen<=15)

typedef __attribute__((ext_vector_type(8))) short short8;
typedef __attribute__((ext_vector_type(4))) float f32x4;

static __device__ __forceinline__ unsigned short bf16bits(float f) {
    __hip_bfloat16 h = __float2bfloat16(f);
    return *(unsigned short*)&h;
}

// f32 lane-row (16-lane) sum via DPP rotate-accumulate: VALU pipe, zero LDS traffic.
// row_ror:N dpp_ctrl = 0x120|N. After ror 8,4,2,1 every lane holds the row total.
template <int CTRL>
static __device__ __forceinline__ float dpp_add(float v) {
    int r = __builtin_amdgcn_update_dpp(0, __builtin_bit_cast(int, v),
                                        CTRL, 0xF, 0xF, true);
    return v + __builtin_bit_cast(float, r);
}
static __device__ __forceinline__ float row_sum16(float v) {
    v = dpp_add<0x128>(v);   // ror 8
    v = dpp_add<0x124>(v);   // ror 4
    v = dpp_add<0x122>(v);   // ror 2
    v = dpp_add<0x121>(v);   // ror 1
    return v;
}

// conv GEMM for ONE l: A[2][4] = relu(conv+bias) for this wave's TWO 16-f tiles.
// ONE af[7] read set feeds BOTH tile MFMAs (this is the 2x LDS-read saving).
// Trailing sched_barrier(0) pins liveness (round-2/3 lesson: keeps peak regs bounded).
#define CONV_ONE(L, A)                                                                     \
    float A[2][4];                                                                         \
    {                                                                                      \
        short8 af[7];                                                                      \
        _Pragma("unroll")                                                                  \
        for (int s = 0; s < 7; s++)                                                        \
            af[s] = *(const short8*)&s_seq[col*SEQ_STRIDE + (L)*CINP + 32*s + quad*8];     \
        f32x4 c0 = {0.f,0.f,0.f,0.f}, c1 = {0.f,0.f,0.f,0.f};                              \
        _Pragma("unroll")                                                                  \
        for (int s = 0; s < 7; s++) {                                                      \
            c0 = __builtin_amdgcn_mfma_f32_16x16x32_bf16(wb[0][s], af[s], c0, 0, 0, 0);    \
            c1 = __builtin_amdgcn_mfma_f32_16x16x32_bf16(wb[1][s], af[s], c1, 0, 0, 0);    \
        }                                                                                  \
        _Pragma("unroll")                                                                  \
        for (int r = 0; r < 4; r++) {                                                      \
            A[0][r] = fmaxf(c0[r] + cbias[0][r], 0.f);                                     \
            A[1][r] = fmaxf(c1[r] + cbias[1][r], 0.f);                                     \
        }                                                                                  \
    }                                                                                      \
    __builtin_amdgcn_sched_barrier(0);

// ---------------- single fused kernel: 16 batch rows / block, 256 threads ----------------
// 4 waves/block; wave w owns TWO conv f-tiles [32w,32w+32) and TWO MLP n-tiles
// [32w,32w+32) (n<64 = n-head, n>=64 = c-head; head is per-tile wave-uniform).
// Rationale vs 8-wave version: af/am LDS fragments depend only on (col,quad,l), so
// 8 waves read identical data 8x. With 2 tiles/wave the same read feeds 2 MFMAs ->
// LDS b128 reads halve. Occupancy: LDS 53.8KB -> 3 blocks/CU; __launch_bounds__(256,3)
// -> ~168-reg budget; peak liveness ~156 -> no scratch spill (WRITE_SIZE must be ~0.13MB).
// Regions (single l per step, straight-line bodies):
//   pre  l=0..9   : conv + sum_n, no barriers
//   mid  l=10..24 : conv + sum_c + tile write + barrier + MLP (15 barrier stages)
//   post l=25..34 : conv + sum_c, no barriers
// __shfl_xor reduces replaced by DPP row_ror adds (VALU pipe, not LDS).
__global__ __launch_bounds__(256, 3) void fused_kernel(
    const float* __restrict__ seq,    const int*   __restrict__ plen_arr,
    const float* __restrict__ conv_w, const float* __restrict__ conv_b,
    const float* __restrict__ n_w1,   const float* __restrict__ n_b1,
    const float* __restrict__ n_w2,   const float* __restrict__ n_b2,
    const float* __restrict__ c_w1,   const float* __restrict__ c_b1,
    const float* __restrict__ c_w2,   const float* __restrict__ c_b2,
    const float* __restrict__ navg_w, const float* __restrict__ navg_b,
    const float* __restrict__ cavg_w, const float* __restrict__ cavg_b,
    const float* __restrict__ out_w,  const float* __restrict__ out_b,
    float* __restrict__ out)
{
    __shared__ __align__(16) unsigned short s_seq[GB * SEQ_STRIDE];      // 34048 B
    __shared__ __align__(16) unsigned short s_tile[4][GB * TILE_STRIDE]; // 17408 B
    __shared__ __align__(16) float s_yp[NYL * 2 * GB];                   // 1920 B: [l-10][head][m]
    // overlay on s_seq (dead after the main loops):
    float* s_avg = (float*)s_seq;            // [4 waves][2][GB] = 128 floats

    const int t    = threadIdx.x;
    const int wave = t >> 6;                 // 0..3
    const int lane = t & 63;
    const int quad = lane >> 4;
    const int col  = lane & 15;
    const int b0   = blockIdx.x * GB;

    // ---- zero-init padded seq (pad rows/channels + slack must be 0) + y accumulator ----
    {
        uint4* p = (uint4*)s_seq;            // 34048/16 = 2128 uint4
        for (int i = t; i < (GB * SEQ_STRIDE) / 8; i += 256)
            p[i] = make_uint4(0u, 0u, 0u, 0u);
        for (int i = t; i < NYL * 2 * GB; i += 256)
            s_yp[i] = 0.0f;
    }

    // ---- per-lane loop-invariant weight fragments: TWO tiles per wave ----
    // conv A-frag (operand-swapped): A[m=f][k=kk], kk = k*24+c
    // MLP  B-frag: B[k=f][n]
    short8 wb[2][7];
    short8 w1b[2][4];
    float  cbias[2][4], b1v[2], w2v[2];
    int    hd[2];
    #pragma unroll
    for (int j = 0; j < 2; j++) {
        const int ng = wave * 32 + j * 16 + col;   // conv f (A m-index) AND mlp n-index
        #pragma unroll
        for (int s = 0; s < 7; s++) {
            short8 v;
            #pragma unroll
            for (int jj = 0; jj < 8; jj++) {
                int kk = 32 * s + quad * 8 + jj;
                int k = kk / CINP, c = kk % CINP;
                float f = (k < Kn && c < CINn) ? conv_w[(k * CINn + c) * Fn + ng] : 0.0f;
                v[jj] = (short)bf16bits(f);
            }
            wb[j][s] = v;
        }
        const int nl = ng & 63;
        const int hj = (wave * 32 + j * 16) >= 64;   // wave-uniform per tile
        #pragma unroll
        for (int s = 0; s < 4; s++) {
            short8 v;
            #pragma unroll
            for (int jj = 0; jj < 8; jj++) {
                int k = 32 * s + quad * 8 + jj;
                float f = hj ? c_w1[k * Hn + nl] : n_w1[k * Hn + nl];
                v[jj] = (short)bf16bits(f);
            }
            w1b[j][s] = v;
        }
        #pragma unroll
        for (int r = 0; r < 4; r++)
            cbias[j][r] = conv_b[wave * 32 + j * 16 + 4 * quad + r];
        b1v[j] = hj ? c_b1[nl] : n_b1[nl];
        w2v[j] = hj ? c_w2[nl] : n_w2[nl];
        hd[j]  = hj;
    }
    const int plen_lane = plen_arr[b0 + col];   // this lane's batch (=col) plen

    __syncthreads();   // zero-init done before data fill

    // ---- stage seq -> bf16 LDS, rows shifted +4 (SAME pad), c<21 only ----
    // incremental (bi,l,c) walk: step 256 = 12 rows + 4 cols (avoids div/mod per iter)
    {
        int i  = t;
        int bi = i / (Ln * CINn);
        int r  = i - bi * (Ln * CINn);
        int l  = r / CINn;
        int c  = r - l * CINn;
        for (; i < GB * Ln * CINn; i += 256) {
            s_seq[bi * SEQ_STRIDE + (4 + l) * CINP + c] =
                bf16bits(seq[(size_t)b0 * (Ln * CINn) + i]);
            c += 4;  if (c >= CINn) { c -= CINn; ++l; }
            l += 12; if (l >= Ln)   { l -= Ln;  ++bi; }
        }
    }
    __syncthreads();

    float sum_n[2][4] = {{0.f,0.f,0.f,0.f},{0.f,0.f,0.f,0.f}};
    float sum_c[2][4] = {{0.f,0.f,0.f,0.f},{0.f,0.f,0.f,0.f}};

    // ======== PRE: l = 0..9, conv + n-flank sum only (no barriers, no LDS writes) ========
    #pragma unroll 1
    for (int l = 0; l < 10; ++l) {
        CONV_ONE(l, a)
        #pragma unroll
        for (int j = 0; j < 2; j++)
            #pragma unroll
            for (int r = 0; r < 4; r++)
                sum_n[j][r] += a[j][r];
    }

    // ======== MID: l = 10..24, conv + c-flank sum + tile write + barrier + MLP ========
    // 4-slot ring on s_tile (slot = l&3): writer for slot returns after 4 barriers;
    // reader (MLP l) finishes before barrier l+1 -> WAR safe.
    #pragma unroll 1
    for (int l = YL0; l <= 24; ++l) {
        CONV_ONE(l, a)
        {
            float cm = (l >= 10 + plen_lane && l < 20 + plen_lane) ? 1.0f : 0.0f;
            #pragma unroll
            for (int j = 0; j < 2; j++)
                #pragma unroll
                for (int r = 0; r < 4; r++)
                    sum_c[j][r] += cm * a[j][r];
        }
        ushort4 pk0 = { bf16bits(a[0][0]), bf16bits(a[0][1]), bf16bits(a[0][2]), bf16bits(a[0][3]) };
        ushort4 pk1 = { bf16bits(a[1][0]), bf16bits(a[1][1]), bf16bits(a[1][2]), bf16bits(a[1][3]) };
        *(ushort4*)&s_tile[l & 3][col * TILE_STRIDE + wave * 32 + 4 * quad]      = pk0;
        *(ushort4*)&s_tile[l & 3][col * TILE_STRIDE + wave * 32 + 16 + 4 * quad] = pk1;
        __syncthreads();   // conv tiles written -> MLP may read; WAR fence for ring

        // ---- MLP layer1 GEMM: ONE am[4] read set feeds BOTH n-tile MFMA chains ----
        short8 am[4];
        #pragma unroll
        for (int s = 0; s < 4; s++)
            am[s] = *(const short8*)&s_tile[l & 3][col * TILE_STRIDE + 32 * s + quad * 8];
        f32x4 h0 = {0.f,0.f,0.f,0.f}, h1 = {0.f,0.f,0.f,0.f};
        #pragma unroll
        for (int s = 0; s < 4; s++) {
            h0 = __builtin_amdgcn_mfma_f32_16x16x32_bf16(am[s], w1b[0][s], h0, 0, 0, 0);
            h1 = __builtin_amdgcn_mfma_f32_16x16x32_bf16(am[s], w1b[1][s], h1, 0, 0, 0);
        }
        // ---- y partial = relu(h+b1) @ w2 over each tile's 16 n; DPP row-sum ----
        float p0[4], p1[4];
        #pragma unroll
        for (int r = 0; r < 4; r++) {
            p0[r] = row_sum16(fmaxf(h0[r] + b1v[0], 0.f) * w2v[0]);
            p1[r] = row_sum16(fmaxf(h1[r] + b1v[1], 0.f) * w2v[1]);
        }
        if (col == 0) {       // 4 lanes/wave (quads); batch index = 4*quad + r
            const int base0 = (l - YL0) * 32 + hd[0] * 16 + quad * 4;
            const int base1 = (l - YL0) * 32 + hd[1] * 16 + quad * 4;
            #pragma unroll
            for (int r = 0; r < 4; r++) atomicAdd(&s_yp[base0 + r], p0[r]);
            #pragma unroll
            for (int r = 0; r < 4; r++) atomicAdd(&s_yp[base1 + r], p1[r]);
        }
        __builtin_amdgcn_sched_barrier(0);
    }

    // ======== POST: l = 25..34, conv + c-flank sum only (no barriers) ========
    #pragma unroll 1
    for (int l = 25; l < Ln; ++l) {
        CONV_ONE(l, a)
        float cm = (l >= 10 + plen_lane && l < 20 + plen_lane) ? 1.0f : 0.0f;
        #pragma unroll
        for (int j = 0; j < 2; j++)
            #pragma unroll
            for (int r = 0; r < 4; r++)
                sum_c[j][r] += cm * a[j][r];
    }
    __syncthreads();   // all s_seq reads + s_yp atomics done -> overlay safe

    // ---- flank-average partials: apply navg_w/cavg_w post-loop ----
    {
        float an = 0.f, ac = 0.f;
        #pragma unroll
        for (int j = 0; j < 2; j++)
            #pragma unroll
            for (int r = 0; r < 4; r++) {
                int fidx = wave * 32 + j * 16 + 4 * quad + r;
                an += sum_n[j][r] * navg_w[fidx];
                ac += sum_c[j][r] * cavg_w[fidx];
            }
        an += __shfl_xor(an, 16); an += __shfl_xor(an, 32);   // sum over quads
        ac += __shfl_xor(ac, 16); ac += __shfl_xor(ac, 32);
        if (quad == 0) {                     // lane < 16: one per batch
            s_avg[wave * 2 * GB + 0 * GB + col] = an;
            s_avg[wave * 2 * GB + 1 * GB + col] = ac;
        }
    }
    // ---- y finalize in place: y = tanh(sum + b2), 480 values, conflict-free ----
    for (int i = t; i < NYL * 2 * GB; i += 256) {
        const int hdd = (i >> 4) & 1;
        s_yp[i] = tanhf(s_yp[i] + (hdd ? c_b2[0] : n_b2[0]));
    }
    __syncthreads();

    // ---- final combine: one thread per batch row ----
    if (t < GB) {
        const int m = t;
        const int plen = plen_arr[b0 + m];
        // s_yp[(l-10)*32 + head*16 + m]; lane m stays in its own bank
        float cleaved_n = s_yp[m];                              // l = 10, n-head
        float mn = 0.f;   // reference maxes (y+1)*mask over ALL l; unmasked give 0
        for (int l = 11; l < 10 + plen; l++)
            mn = fmaxf(mn, s_yp[(l - YL0) * 32 + m] + 1.f);
        float maxpool_n = -(mn - 1.f);
        float cleaved_c = s_yp[(plen - 1) * 32 + 16 + m];       // l = 10+plen-1, c-head
        float mc = 0.f;
        for (int l = 10; l < 10 + plen - 1; l++)
            mc = fmaxf(mc, s_yp[(l - YL0) * 32 + 16 + m] + 1.f);
        float maxpool_c = -(mc - 1.f);
        float sn = 0.f, sc = 0.f;
        #pragma unroll
        for (int w = 0; w < 4; w++) {
            sn += s_avg[w * 2 * GB + 0 * GB + m];
            sc += s_avg[w * 2 * GB + 1 * GB + m];
        }
        float avg_n = tanhf(sn * 0.1f + navg_b[0]);
        float avg_c = tanhf(sc * 0.1f + cavg_b[0]);
        float comb = cleaved_n * out_w[0] + maxpool_n * out_w[1] + avg_n * out_w[2]
                   + cleaved_c * out_w[3] + maxpool_c * out_w[4] + avg_c * out_w[5]
                   + out_b[0];
        out[b0 + m] = 1.f / (1.f + expf(-comb));
    }
}

extern "C" void kernel_launch(void* const* d_in, const int* in_sizes, int n_in,
                              void* d_out, int out_size, void* d_ws, size_t ws_size,
                              hipStream_t stream) {
    const int B = in_sizes[1];
    fused_kernel<<<B / GB, 256, 0, stream>>>(
        (const float*)d_in[0],  (const int*)d_in[1],
        (const float*)d_in[2],  (const float*)d_in[3],
        (const float*)d_in[4],  (const float*)d_in[5],
        (const float*)d_in[6],  (const float*)d_in[7],
        (const float*)d_in[8],  (const float*)d_in[9],
        (const float*)d_in[10], (const float*)d_in[11],
        (const float*)d_in[12], (const float*)d_in[13],
        (const float*)d_in[14], (const float*)d_in[15],
        (const float*)d_in[16], (const float*)d_in[17],
        (float*)d_out);
}

// Round 5
// 356.211 us; speedup vs baseline: 1.3176x; 1.3176x over previous
//
#include <hip/hip_runtime.h>
#include <hip/hip_bf16.h>
#include <math.h>

// Problem constants
#define Ln     35
#define CINn   21
#define CINP   24        // padded CIN (multiple of 8 -> aligned b128 im2col reads)
#define Fn     128
#define Kn     9
#define Hn     64
#define GB     16        // batch rows per block
#define SEQ_STRIDE 1064  // 44 rows*24 + 8 slack (shorts); l=35 window ends at 1064
#define TILE_STRIDE 136  // 128 + 8 pad (shorts)
#define YP_STRIDE 136    // floats per l in s_yp: 8 waves*16 batch + 8 pad (bank decorrelate)

typedef __attribute__((ext_vector_type(8))) short short8;
typedef __attribute__((ext_vector_type(4))) float f32x4;

static __device__ __forceinline__ unsigned short bf16bits(float f) {
    __hip_bfloat16 h = __float2bfloat16(f);
    return *(unsigned short*)&h;
}

// f32 lane-row (16-lane) sum via DPP rotate-accumulate: VALU pipe, zero LDS traffic.
// row_ror:N dpp_ctrl = 0x120|N. After ror 8,4,2,1 every lane holds the row total.
// (numerically validated in round 4; replaces 4x ds_swizzle per value)
template <int CTRL>
static __device__ __forceinline__ float dpp_add(float v) {
    int r = __builtin_amdgcn_update_dpp(0, __builtin_bit_cast(int, v),
                                        CTRL, 0xF, 0xF, true);
    return v + __builtin_bit_cast(float, r);
}
static __device__ __forceinline__ float row_sum16(float v) {
    v = dpp_add<0x128>(v);   // ror 8
    v = dpp_add<0x124>(v);   // ror 4
    v = dpp_add<0x122>(v);   // ror 2
    v = dpp_add<0x121>(v);   // ror 1
    return v;
}

// ---------------- single fused kernel: 16 batch rows / block, 512 threads ----------------
// 8 waves/block; wave w owns conv f-tile [16w,16w+16) and MLP n-tile [16w,16w+16)
// (n<64 = n-head, n>=64 = c-head). Weight frags per wave: 28+16 = 44 VGPRs.
// NOTE (rounds 1-4 lesson): this uniform-loop structure is the only one verified
// spill-free (WRITE_SIZE == output). Do not peel regions or add branches around the
// barrier without re-checking WRITE_SIZE. This round: round-0 structure + DPP reduce
// + padded s_yp stride + m-fastest finalize (expression-level edits only).
__global__ __launch_bounds__(512, 4) void fused_kernel(
    const float* __restrict__ seq,    const int*   __restrict__ plen_arr,
    const float* __restrict__ conv_w, const float* __restrict__ conv_b,
    const float* __restrict__ n_w1,   const float* __restrict__ n_b1,
    const float* __restrict__ n_w2,   const float* __restrict__ n_b2,
    const float* __restrict__ c_w1,   const float* __restrict__ c_b1,
    const float* __restrict__ c_w2,   const float* __restrict__ c_b2,
    const float* __restrict__ navg_w, const float* __restrict__ navg_b,
    const float* __restrict__ cavg_w, const float* __restrict__ cavg_b,
    const float* __restrict__ out_w,  const float* __restrict__ out_b,
    float* __restrict__ out)
{
    __shared__ __align__(16) unsigned short s_seq[GB * SEQ_STRIDE];      // 34048 B
    __shared__ __align__(16) unsigned short s_tile[4][GB * TILE_STRIDE]; // 17408 B
    __shared__ __align__(16) float s_yp[Ln * YP_STRIDE];                 // 19040 B: [l][wave*16+m]
    // overlays on s_seq (dead after the main loop):
    float* s_y   = (float*)s_seq;            // [2][GB][36] = 1152 floats
    float* s_avg = (float*)s_seq + 1152;     // [8 waves][2][GB] = 256 floats

    const int t    = threadIdx.x;
    const int wave = t >> 6;                 // 0..7
    const int lane = t & 63;
    const int quad = lane >> 4;
    const int col  = lane & 15;
    const int b0   = blockIdx.x * GB;

    // ---- zero-init padded seq (pad rows/channels + slack must be 0) ----
    {
        uint4* p = (uint4*)s_seq;            // 34048/16 = 2128 uint4
        for (int i = t; i < (GB * SEQ_STRIDE) / 8; i += 512)
            p[i] = make_uint4(0u, 0u, 0u, 0u);
    }

    // ---- per-lane loop-invariant weight fragments (single tile per wave) ----
    // conv A-frag (operand-swapped): A[m=f=16*wave+col][k=kk], kk = k*24+c
    // MLP  B-frag: B[k=f][n=16*wave+col]
    short8 wb[7];
    short8 w1b[4];
    float  cbias[4], b1v, w2v;
    const int head = wave >> 2;              // 0 = n-head (waves 0-3), 1 = c (waves 4-7)
    {
        const int ng = wave * 16 + col;      // conv f (A m-index) AND mlp n-index
        #pragma unroll
        for (int s = 0; s < 7; s++) {
            short8 v;
            #pragma unroll
            for (int j = 0; j < 8; j++) {
                int kk = 32 * s + quad * 8 + j;
                int k = kk / CINP, c = kk % CINP;
                float f = (k < Kn && c < CINn) ? conv_w[(k * CINn + c) * Fn + ng] : 0.0f;
                v[j] = (short)bf16bits(f);
            }
            wb[s] = v;
        }
        const int nl = ng & 63;
        #pragma unroll
        for (int s = 0; s < 4; s++) {
            short8 v;
            #pragma unroll
            for (int j = 0; j < 8; j++) {
                int k = 32 * s + quad * 8 + j;
                float f = head ? c_w1[k * Hn + nl] : n_w1[k * Hn + nl];
                v[j] = (short)bf16bits(f);
            }
            w1b[s] = v;
        }
        #pragma unroll
        for (int r = 0; r < 4; r++)
            cbias[r] = conv_b[wave * 16 + 4 * quad + r];
        b1v = head ? c_b1[nl] : n_b1[nl];
        w2v = head ? c_w2[nl] : n_w2[nl];
    }
    const int plen_lane = plen_arr[b0 + col];   // this lane's batch (=col) plen

    __syncthreads();   // zero-init done before data fill

    // ---- stage seq -> bf16 LDS, rows shifted +4 (SAME pad), c<21 only ----
    for (int i = t; i < GB * Ln * CINn; i += 512) {
        int bi = i / (Ln * CINn), r = i % (Ln * CINn);
        int l = r / CINn, c = r % CINn;
        s_seq[bi * SEQ_STRIDE + (4 + l) * CINP + c] =
            bf16bits(seq[(size_t)(b0 + bi) * (Ln * CINn) + r]);
    }
    __syncthreads();

    float sum_n[4] = {0.f,0.f,0.f,0.f};
    float sum_c[4] = {0.f,0.f,0.f,0.f};

    // ---- main loop: 2 l per stage, 18 stages, 1 barrier each. 4-slot ring:
    // stage i writes slots {2i&3,(2i+1)&3}; WAR on a slot is fenced 1 stage later.
    // l=35 is a computed pad column (auto-masked from sums; y-write guarded).
    for (int l0 = 0; l0 < 36; l0 += 2) {
        const int l1 = l0 + 1;
        // ---- conv GEMM (operand-swapped): D^T[f][batch], wave's 16-f tile ----
        short8 af0[7], af1[7];
        #pragma unroll
        for (int s = 0; s < 7; s++) {
            af0[s] = *(const short8*)&s_seq[col * SEQ_STRIDE + l0 * CINP + 32 * s + quad * 8];
            af1[s] = *(const short8*)&s_seq[col * SEQ_STRIDE + l1 * CINP + 32 * s + quad * 8];
        }
        f32x4 cacc0 = {0.f,0.f,0.f,0.f};
        f32x4 cacc1 = {0.f,0.f,0.f,0.f};
        #pragma unroll
        for (int s = 0; s < 7; s++) {
            cacc0 = __builtin_amdgcn_mfma_f32_16x16x32_bf16(wb[s], af0[s], cacc0, 0, 0, 0);
            cacc1 = __builtin_amdgcn_mfma_f32_16x16x32_bf16(wb[s], af1[s], cacc1, 0, 0, 0);
        }
        // ---- epilogue: lane holds batch=col, f = 16*wave + 4q + r ----
        {
            float cm0 = (l0 >= 10 + plen_lane && l0 < 20 + plen_lane) ? 1.0f : 0.0f;
            float cm1 = (l1 >= 10 + plen_lane && l1 < 20 + plen_lane) ? 1.0f : 0.0f;
            float a0 = fmaxf(cacc0[0] + cbias[0], 0.0f);
            float a1 = fmaxf(cacc0[1] + cbias[1], 0.0f);
            float a2 = fmaxf(cacc0[2] + cbias[2], 0.0f);
            float a3 = fmaxf(cacc0[3] + cbias[3], 0.0f);
            float e0 = fmaxf(cacc1[0] + cbias[0], 0.0f);
            float e1 = fmaxf(cacc1[1] + cbias[1], 0.0f);
            float e2 = fmaxf(cacc1[2] + cbias[2], 0.0f);
            float e3 = fmaxf(cacc1[3] + cbias[3], 0.0f);
            if (l0 < 10) {            // wave-uniform
                sum_n[0] += a0; sum_n[1] += a1; sum_n[2] += a2; sum_n[3] += a3;
            }
            if (l1 < 10) {
                sum_n[0] += e0; sum_n[1] += e1; sum_n[2] += e2; sum_n[3] += e3;
            }
            sum_c[0] += cm0 * a0 + cm1 * e0;
            sum_c[1] += cm0 * a1 + cm1 * e1;
            sum_c[2] += cm0 * a2 + cm1 * e2;
            sum_c[3] += cm0 * a3 + cm1 * e3;
            ushort4 pk0 = { bf16bits(a0), bf16bits(a1), bf16bits(a2), bf16bits(a3) };
            ushort4 pk1 = { bf16bits(e0), bf16bits(e1), bf16bits(e2), bf16bits(e3) };
            *(ushort4*)&s_tile[l0 & 3][col * TILE_STRIDE + wave * 16 + 4 * quad] = pk0;
            *(ushort4*)&s_tile[l1 & 3][col * TILE_STRIDE + wave * 16 + 4 * quad] = pk1;
        }
        __syncthreads();   // conv tiles written -> MLP may read; WAR fence for ring

        // ---- MLP layer1 GEMM: D[m=batch][n = wave's 16-n tile], K = 128 f ----
        short8 am0[4], am1[4];
        #pragma unroll
        for (int s = 0; s < 4; s++) {
            am0[s] = *(const short8*)&s_tile[l0 & 3][col * TILE_STRIDE + 32 * s + quad * 8];
            am1[s] = *(const short8*)&s_tile[l1 & 3][col * TILE_STRIDE + 32 * s + quad * 8];
        }
        f32x4 hacc0 = {0.f,0.f,0.f,0.f};
        f32x4 hacc1 = {0.f,0.f,0.f,0.f};
        #pragma unroll
        for (int s = 0; s < 4; s++) {
            hacc0 = __builtin_amdgcn_mfma_f32_16x16x32_bf16(am0[s], w1b[s], hacc0, 0, 0, 0);
            hacc1 = __builtin_amdgcn_mfma_f32_16x16x32_bf16(am1[s], w1b[s], hacc1, 0, 0, 0);
        }
        // ---- y partial = relu(h+b1) @ w2 over this wave's 16 n; DPP row-sum ----
        float p0[4], p1[4];
        #pragma unroll
        for (int r = 0; r < 4; r++) {
            p0[r] = row_sum16(fmaxf(hacc0[r] + b1v, 0.f) * w2v);
            p1[r] = row_sum16(fmaxf(hacc1[r] + b1v, 0.f) * w2v);
        }
        if (col == 0) {                      // batch index = 4*quad + r
            *(f32x4*)&s_yp[l0 * YP_STRIDE + wave * 16 + quad * 4] =
                (f32x4){p0[0], p0[1], p0[2], p0[3]};
            if (l1 < Ln)
                *(f32x4*)&s_yp[l1 * YP_STRIDE + wave * 16 + quad * 4] =
                    (f32x4){p1[0], p1[1], p1[2], p1[3]};
        }
    }
    __syncthreads();   // all s_seq reads done -> overlay safe; s_yp complete

    // ---- flank-average partials: apply navg_w/cavg_w post-loop ----
    {
        float an = 0.f, ac = 0.f;
        #pragma unroll
        for (int r = 0; r < 4; r++) {
            int fidx = wave * 16 + 4 * quad + r;
            an += sum_n[r] * navg_w[fidx];
            ac += sum_c[r] * cavg_w[fidx];
        }
        an += __shfl_xor(an, 16); an += __shfl_xor(an, 32);   // sum over quads
        ac += __shfl_xor(ac, 16); ac += __shfl_xor(ac, 32);
        if (quad == 0) {                     // lane < 16: one per batch
            s_avg[wave * 2 * GB + 0 * GB + col] = an;
            s_avg[wave * 2 * GB + 1 * GB + col] = ac;
        }
    }
    __syncthreads();

    // ---- y finalize: y = tanh(sum of 4 wave-partials + b2), 1120 values ----
    // m-fastest decomposition: 64 lanes cover all 32 banks 2-way (conflict-free);
    // YP_STRIDE=136 decorrelates the per-l bank offset (136%32 = 8).
    {
        const float bn = n_b2[0], bc = c_b2[0];
        for (int i = t; i < 2 * GB * Ln; i += 512) {
            int m = i & 15, rem = i >> 4;        // rem = 0..69
            int l = rem % Ln, hd = rem / Ln;
            float v = (hd ? bc : bn);
            #pragma unroll
            for (int w = 0; w < 4; w++)
                v += s_yp[l * YP_STRIDE + (hd * 4 + w) * 16 + m];
            s_y[hd * GB * 36 + m * 36 + l] = tanhf(v);
        }
    }
    __syncthreads();

    // ---- final combine: one thread per batch row ----
    if (t < GB) {
        const int m = t;
        const int plen = plen_arr[b0 + m];
        const float* ym = s_y + m * 36;               // n-head row
        const float* yc = s_y + GB * 36 + m * 36;     // c-head row
        float cleaved_n = ym[10];
        float mn = 0.f;   // reference maxes (y+1)*mask over ALL l; unmasked give 0
        for (int l = 11; l < 10 + plen; l++) mn = fmaxf(mn, ym[l] + 1.f);
        float maxpool_n = -(mn - 1.f);
        float cleaved_c = yc[10 + plen - 1];
        float mc = 0.f;
        for (int l = 10; l < 10 + plen - 1; l++) mc = fmaxf(mc, yc[l] + 1.f);
        float maxpool_c = -(mc - 1.f);
        float sn = 0.f, sc = 0.f;
        #pragma unroll
        for (int w = 0; w < 8; w++) {
            sn += s_avg[w * 2 * GB + 0 * GB + m];
            sc += s_avg[w * 2 * GB + 1 * GB + m];
        }
        float avg_n = tanhf(sn * 0.1f + navg_b[0]);
        float avg_c = tanhf(sc * 0.1f + cavg_b[0]);
        float comb = cleaved_n * out_w[0] + maxpool_n * out_w[1] + avg_n * out_w[2]
                   + cleaved_c * out_w[3] + maxpool_c * out_w[4] + avg_c * out_w[5]
                   + out_b[0];
        out[b0 + m] = 1.f / (1.f + expf(-comb));
    }
}

extern "C" void kernel_launch(void* const* d_in, const int* in_sizes, int n_in,
                              void* d_out, int out_size, void* d_ws, size_t ws_size,
                              hipStream_t stream) {
    const int B = in_sizes[1];
    fused_kernel<<<B / GB, 512, 0, stream>>>(
        (const float*)d_in[0],  (const int*)d_in[1],
        (const float*)d_in[2],  (const float*)d_in[3],
        (const float*)d_in[4],  (const float*)d_in[5],
        (const float*)d_in[6],  (const float*)d_in[7],
        (const float*)d_in[8],  (const float*)d_in[9],
        (const float*)d_in[10], (const float*)d_in[11],
        (const float*)d_in[12], (const float*)d_in[13],
        (const float*)d_in[14], (const float*)d_in[15],
        (const float*)d_in[16], (const float*)d_in[17],
        (float*)d_out);
}